// Round 5
// baseline (1428.512 us; speedup 1.0000x reference)
//
#include <hip/hip_runtime.h>
#include <math.h>

// Problem constants (from setup_inputs)
#define N_NODES 4096
#define BATCH   32
#define D_EMB   10
#define CIN     2
#define COUT    64
#define CI      66          // CIN + COUT
#define KSUP    3
#define NCOLS   2112        // BATCH * CI
#define NPAD    2176        // NCOLS padded to 17*128 tiles
#define LDT     4096        // t-layout row stride (m contiguous)
#define OCH     16          // (fallback path) outputs per transform block chunk

// MFMA-transform constants
#define KI_REAL 198         // KSUP*CI
#define KI_MMA  224         // 7 * 32 (k-steps)
#define KILD    232         // storage/LDS row stride (bank-conflict pad, mult of 8)
#define WROW_G  (128 * KILD)   // 29696: gate Wn row length per node
#define WROW_U  (64 * KILD)    // 14848: update Wn row length per node
#define WGT2_R  (WROW_G + WROW_U)  // 44544 rows in Wgt2

typedef _Float16 half_t;
typedef __attribute__((ext_vector_type(8))) _Float16 f16x8;
typedef __attribute__((ext_vector_type(4))) _Float16 f16x4;
typedef __attribute__((ext_vector_type(4))) float f32x4;

__device__ __forceinline__ float fast_sigmoid(float x) { return 1.f / (1.f + __expf(-x)); }
__device__ __forceinline__ float fast_tanh(float x) { return 1.f - 2.f / (__expf(2.f * x) + 1.f); }

__device__ __forceinline__ void gld_lds16(const half_t* g, half_t* l) {
  __builtin_amdgcn_global_load_lds(
      (const __attribute__((address_space(1))) void*)g,
      (__attribute__((address_space(3))) void*)l, 16, 0, 0);
}

// ---------------------------------------------------------------------------
// P[n,m] = softmax_m(relu(E[n,:].E[m,:])) stored directly as fp16.
// ---------------------------------------------------------------------------
__global__ __launch_bounds__(256) void k_softmax_p(const float* __restrict__ E,
                                                   half_t* __restrict__ Pb) {
  const int n = blockIdx.x;
  const int tid = threadIdx.x;
  __shared__ float En[D_EMB];
  __shared__ float ms[256], ss[256];
  if (tid < D_EMB) En[tid] = E[n * D_EMB + tid];
  __syncthreads();
  float en[D_EMB];
#pragma unroll
  for (int d = 0; d < D_EMB; ++d) en[d] = En[d];

  float m = -1e30f, s = 0.f;
  for (int c = tid; c < N_NODES; c += 256) {
    const float* Ec = E + c * D_EMB;
    float v = 0.f;
#pragma unroll
    for (int d = 0; d < D_EMB; ++d) v += en[d] * Ec[d];
    v = fmaxf(v, 0.f);
    if (v > m) { s *= __expf(m - v); m = v; }
    s += __expf(v - m);
  }
  ms[tid] = m; ss[tid] = s;
  __syncthreads();
  for (int off = 128; off > 0; off >>= 1) {
    if (tid < off) {
      float m2 = ms[tid + off], s2 = ss[tid + off];
      float m1 = ms[tid], s1 = ss[tid];
      float mm = fmaxf(m1, m2);
      ms[tid] = mm;
      ss[tid] = s1 * __expf(m1 - mm) + s2 * __expf(m2 - mm);
    }
    __syncthreads();
  }
  const float M = ms[0];
  const float inv = 1.f / ss[0];
  half_t* Pr = Pb + (size_t)n * N_NODES;
  for (int c = tid; c < N_NODES; c += 256) {
    const float* Ec = E + c * D_EMB;
    float v = 0.f;
#pragma unroll
    for (int d = 0; d < D_EMB; ++d) v += en[d] * Ec[d];
    v = fmaxf(v, 0.f);
    Pr[c] = (half_t)(__expf(v - M) * inv);
  }
}

// ---------------------------------------------------------------------------
// Build V0 in both layouts (+ X part of Cb in both layouts), fp16.
// ---------------------------------------------------------------------------
__global__ __launch_bounds__(256) void k_build_v0(const float* __restrict__ X,
                                                  const float* __restrict__ H,
                                                  half_t* __restrict__ Vt,
                                                  half_t* __restrict__ Vn,
                                                  half_t* __restrict__ Cbt,
                                                  half_t* __restrict__ Cbn) {
  size_t idx = (size_t)blockIdx.x * 256 + threadIdx.x;
  if (idx >= (size_t)N_NODES * NCOLS) return;
  const int m = (int)(idx / NCOLS);
  const int col = (int)(idx % NCOLS);
  const int b = col / CI;
  const int c = col % CI;
  float v;
  if (c < CIN) v = X[((size_t)b * N_NODES + m) * CIN + c];
  else         v = H[((size_t)b * N_NODES + m) * COUT + (c - CIN)];
  const half_t h = (half_t)v;
  Vn[(size_t)m * NPAD + col] = h;
  Vt[(size_t)col * LDT + m] = h;
  if (c < CIN) {
    Cbn[(size_t)m * NPAD + col] = h;
    Cbt[(size_t)col * LDT + m] = h;
  }
}

// ---------------------------------------------------------------------------
// fp16 MFMA NT-GEMM (verified in R4): C[m][n] = sum_k A[m][k] * Bt[n][k]
// ---------------------------------------------------------------------------
__global__ __launch_bounds__(256) void k_gemm_f16(const half_t* __restrict__ A,
                                                  const half_t* __restrict__ Bt,
                                                  half_t* __restrict__ Cn,
                                                  half_t* __restrict__ Ct) {
  __shared__ half_t As[128 * 32];
  __shared__ half_t Bs[128 * 32];
  const int tid = threadIdx.x;
  const int lane = tid & 63;
  const int wave = tid >> 6;
  const int wm = (wave >> 1) * 64;
  const int wn = (wave & 1) * 64;
  const int rb = blockIdx.y * 128;
  const int cb = blockIdx.x * 128;

  const int srow = (lane >> 2);
  const int skg = (lane & 3) * 8;
  const half_t* ga0 = A + (size_t)(rb + wave * 32 + srow) * N_NODES + skg;
  const half_t* ga1 = ga0 + (size_t)16 * N_NODES;
  const half_t* gb0 = Bt + (size_t)(cb + wave * 32 + srow) * LDT + skg;
  const half_t* gb1 = gb0 + (size_t)16 * LDT;
  half_t* lA0 = As + wave * 1024;
  half_t* lA1 = lA0 + 512;
  half_t* lB0 = Bs + wave * 1024;
  half_t* lB1 = lB0 + 512;

  const int fr = lane & 15;
  const int fk = (lane >> 4) * 8;

  f32x4 acc[4][4] = {};

  for (int k0 = 0; k0 < N_NODES; k0 += 32) {
    __syncthreads();
    gld_lds16(ga0 + k0, lA0);
    gld_lds16(ga1 + k0, lA1);
    gld_lds16(gb0 + k0, lB0);
    gld_lds16(gb1 + k0, lB1);
    __syncthreads();

    f16x8 a[4], b[4];
#pragma unroll
    for (int i = 0; i < 4; ++i)
      a[i] = *(const f16x8*)&As[(wm + i * 16 + fr) * 32 + fk];
#pragma unroll
    for (int j = 0; j < 4; ++j)
      b[j] = *(const f16x8*)&Bs[(wn + j * 16 + fr) * 32 + fk];
#pragma unroll
    for (int i = 0; i < 4; ++i)
#pragma unroll
      for (int j = 0; j < 4; ++j)
        acc[i][j] = __builtin_amdgcn_mfma_f32_16x16x32_f16(a[i], b[j], acc[i][j], 0, 0, 0);
  }

  const int en = lane & 15;
  const int em = (lane >> 4) * 4;
#pragma unroll
  for (int i = 0; i < 4; ++i) {
#pragma unroll
    for (int j = 0; j < 4; ++j) {
      const int m0 = rb + wm + i * 16 + em;
      const int n = cb + wn + j * 16 + en;
      half_t h0 = (half_t)acc[i][j][0];
      half_t h1 = (half_t)acc[i][j][1];
      half_t h2 = (half_t)acc[i][j][2];
      half_t h3 = (half_t)acc[i][j][3];
      f16x4 t4 = {h0, h1, h2, h3};
      *(f16x4*)&Ct[(size_t)n * LDT + m0] = t4;
      Cn[(size_t)(m0 + 0) * NPAD + n] = h0;
      Cn[(size_t)(m0 + 1) * NPAD + n] = h1;
      Cn[(size_t)(m0 + 2) * NPAD + n] = h2;
      Cn[(size_t)(m0 + 3) * NPAD + n] = h3;
    }
  }
}

// ===========================================================================
// BIG-WS PATH: materialized per-node adaptive weights + MFMA transforms
// ===========================================================================

// Wgt2[row][32] fp16: row < WROW_G: gate (o=row/KILD, ki=row%KILD);
// else update. ki>=198 or d>=10 -> 0. Value = pool[d][k][i][o].
__global__ __launch_bounds__(256) void k_wgt2(const float* __restrict__ Wg,
                                              const float* __restrict__ Wu,
                                              half_t* __restrict__ Wgt2) {
  const int r = blockIdx.x * 256 + threadIdx.x;
  if (r >= WGT2_R) return;
  const float* pool;
  int o, ki, ostr;
  if (r < WROW_G) { o = r / KILD; ki = r % KILD; pool = Wg; ostr = 128; }
  else { int r2 = r - WROW_G; o = r2 / KILD; ki = r2 % KILD; pool = Wu; ostr = 64; }
  half_t vals[32];
#pragma unroll
  for (int d = 0; d < 32; ++d) vals[d] = (half_t)0.f;
  if (ki < KI_REAL) {
    const int k = ki / CI;
    const int i = ki % CI;
#pragma unroll
    for (int d = 0; d < D_EMB; ++d)
      vals[d] = (half_t)pool[(((size_t)d * KSUP + k) * CI + i) * ostr + o];
  }
#pragma unroll
  for (int e = 0; e < 4; ++e)
    *(f16x8*)&Wgt2[(size_t)r * 32 + e * 8] = *(f16x8*)&vals[e * 8];
}

// E2[n][32] fp16 = E[n][d] padded with zeros (d>=10).
__global__ __launch_bounds__(256) void k_e2(const float* __restrict__ E,
                                            half_t* __restrict__ E2) {
  const int idx = blockIdx.x * 256 + threadIdx.x;  // over 4096*32
  if (idx >= N_NODES * 32) return;
  const int n = idx >> 5;
  const int d = idx & 31;
  E2[idx] = (d < D_EMB) ? (half_t)E[n * D_EMB + d] : (half_t)0.f;
}

// Wn GEMM: Wn[node][ncol] = sum_d Wgt2[ncol][d] * E2[node][d]  (K=32 MFMA)
// Block: 64 ncols (4 m-tiles, 1/wave) x 256 nodes (16 n-tiles). Direct-global frags.
__global__ __launch_bounds__(256) void k_wn(const half_t* __restrict__ A,  // Wgt2 (+offset)
                                            const half_t* __restrict__ E2,
                                            half_t* __restrict__ Wn,
                                            int row_len) {
  const int tid = threadIdx.x;
  const int lane = tid & 63;
  const int wave = tid >> 6;
  const int fr = lane & 15;
  const int fk = (lane >> 4) * 8;
  const int mt = blockIdx.x * 4 + wave;         // m-tile (16 ncols)
  const int node0 = blockIdx.y * 256;

  const f16x8 a = *(const f16x8*)&A[(size_t)(mt * 16 + fr) * 32 + fk];
  const int en = lane & 15;
  const int em = (lane >> 4) * 4;
#pragma unroll
  for (int j = 0; j < 16; ++j) {
    const f16x8 b = *(const f16x8*)&E2[(size_t)(node0 + j * 16 + fr) * 32 + fk];
    f32x4 acc = {0.f, 0.f, 0.f, 0.f};
    acc = __builtin_amdgcn_mfma_f32_16x16x32_f16(a, b, acc, 0, 0, 0);
    const int node = node0 + j * 16 + en;
    const int ncol = mt * 16 + em;
    f16x4 t4 = {(half_t)acc[0], (half_t)acc[1], (half_t)acc[2], (half_t)acc[3]};
    *(f16x4*)&Wn[(size_t)node * row_len + ncol] = t4;
  }
}

// Gate transform (MFMA): per node, ZR[b][o] = sigmoid(sum_ki XG[b][ki]*W[o][ki] + bias[o])
__global__ __launch_bounds__(256) void k_gate_t(const half_t* __restrict__ Vn,
                                                const half_t* __restrict__ G1n,
                                                const half_t* __restrict__ G2n,
                                                const half_t* __restrict__ Wn,
                                                const float* __restrict__ E,
                                                const float* __restrict__ bg,
                                                const float* __restrict__ H,
                                                half_t* __restrict__ Cbn,
                                                half_t* __restrict__ Cbt,
                                                float* __restrict__ Rb) {
  const int n = blockIdx.x;
  const int tid = threadIdx.x;
  const int lane = tid & 63;
  const int wave = tid >> 6;
  __shared__ half_t Wl[128 * KILD];   // 59392 B
  __shared__ half_t xg[32 * KILD];    // 14848 B
  __shared__ float biasl[128];

  // 1) stage W slice (linear 59392 B copy; 58 chunks of 1024B -> 14.5/wave)
  const half_t* wg = Wn + (size_t)n * WROW_G;
  {
    // 128*KILD*2 = 59392 B = 58 chunks; assign q = wave + 4*j, j<15, q<58
#pragma unroll
    for (int j = 0; j < 15; ++j) {
      const int q = wave + 4 * j;
      if (q < 58) gld_lds16(wg + q * 512 + lane * 8, Wl + q * 512);
    }
  }
  // 2) bias
  if (tid < 128) {
    float s = 0.f;
#pragma unroll
    for (int d = 0; d < D_EMB; ++d) s += E[n * D_EMB + d] * bg[d * 128 + tid];
    biasl[tid] = s;
  }
  // 3) stage xg[b][ki]: ki = k*66+i; pad [198,232) zeros
  {
    const half_t* v0r = Vn + (size_t)n * NPAD;
    const half_t* g1r = G1n + (size_t)n * NPAD;
    const half_t* g2r = G2n + (size_t)n * NPAD;
    for (int idx = tid; idx < NCOLS / 8; idx += 256) {   // 264 octets
      const f16x8 v0 = *(const f16x8*)&v0r[idx * 8];
      const f16x8 g1 = *(const f16x8*)&g1r[idx * 8];
      const f16x8 g2 = *(const f16x8*)&g2r[idx * 8];
      const f16x8 x2 = g2 + g2 - v0;
#pragma unroll
      for (int e = 0; e < 8; ++e) {
        const int col = idx * 8 + e;
        const int b = col / CI;
        const int i = col - b * CI;
        xg[b * KILD + i] = v0[e];
        xg[b * KILD + CI + i] = g1[e];
        xg[b * KILD + 2 * CI + i] = x2[e];
      }
    }
    for (int z = tid; z < 32 * 17; z += 256) {   // zero ki in [198,232): 17 u32/b
      const int b = z / 17;
      const int j = z - b * 17;
      *(unsigned*)&xg[b * KILD + KI_REAL + j * 2] = 0u;
    }
  }
  __syncthreads();

  // 4) MFMA: wave w -> o-range [w*32, w*32+32); m-tiles b 0..31
  const int fr = lane & 15;
  const int fk = (lane >> 4) * 8;
  f32x4 acc[2][2] = {};
#pragma unroll
  for (int ks = 0; ks < 7; ++ks) {
    const f16x8 a0 = *(const f16x8*)&xg[fr * KILD + ks * 32 + fk];
    const f16x8 a1 = *(const f16x8*)&xg[(16 + fr) * KILD + ks * 32 + fk];
    const f16x8 b0 = *(const f16x8*)&Wl[(wave * 32 + fr) * KILD + ks * 32 + fk];
    const f16x8 b1 = *(const f16x8*)&Wl[(wave * 32 + 16 + fr) * KILD + ks * 32 + fk];
    acc[0][0] = __builtin_amdgcn_mfma_f32_16x16x32_f16(a0, b0, acc[0][0], 0, 0, 0);
    acc[0][1] = __builtin_amdgcn_mfma_f32_16x16x32_f16(a0, b1, acc[0][1], 0, 0, 0);
    acc[1][0] = __builtin_amdgcn_mfma_f32_16x16x32_f16(a1, b0, acc[1][0], 0, 0, 0);
    acc[1][1] = __builtin_amdgcn_mfma_f32_16x16x32_f16(a1, b1, acc[1][1], 0, 0, 0);
  }

  // 5) epilogue: col(en)=o within tile, rows = b. waves 0,1 -> Z; 2,3 -> R.
  const int en = lane & 15;
  const int em = (lane >> 4) * 4;
#pragma unroll
  for (int i = 0; i < 2; ++i) {
#pragma unroll
    for (int j = 0; j < 2; ++j) {
      const int o = wave * 32 + j * 16 + en;
      const float bo = biasl[o];
#pragma unroll
      for (int r = 0; r < 4; ++r) {
        const int b = i * 16 + em + r;
        const float s = fast_sigmoid(acc[i][j][r] + bo);
        if (wave < 2) {
          const float h = H[((size_t)b * N_NODES + n) * COUT + o];
          const half_t z = (half_t)(s * h);
          const int c0 = b * CI + CIN + o;
          Cbn[(size_t)n * NPAD + c0] = z;
          Cbt[(size_t)c0 * LDT + n] = z;
        } else {
          Rb[((size_t)b * N_NODES + n) * COUT + (o - 64)] = s;
        }
      }
    }
  }
}

// Update transform (MFMA) + final gating.
__global__ __launch_bounds__(256) void k_update_t(const half_t* __restrict__ Cbn,
                                                  const half_t* __restrict__ G1n,
                                                  const half_t* __restrict__ G2n,
                                                  const half_t* __restrict__ Wn,
                                                  const float* __restrict__ E,
                                                  const float* __restrict__ bu,
                                                  const float* __restrict__ H,
                                                  const float* __restrict__ Rb,
                                                  float* __restrict__ Out) {
  const int n = blockIdx.x;
  const int tid = threadIdx.x;
  const int lane = tid & 63;
  const int wave = tid >> 6;
  __shared__ half_t Wl[64 * KILD];    // 29696 B
  __shared__ half_t xg[32 * KILD];
  __shared__ float biasl[64];

  const half_t* wg = Wn + (size_t)n * WROW_U;
  {
    // 29696 B = 29 chunks
#pragma unroll
    for (int j = 0; j < 8; ++j) {
      const int q = wave + 4 * j;
      if (q < 29) gld_lds16(wg + q * 512 + lane * 8, Wl + q * 512);
    }
  }
  if (tid < 64) {
    float s = 0.f;
#pragma unroll
    for (int d = 0; d < D_EMB; ++d) s += E[n * D_EMB + d] * bu[d * 64 + tid];
    biasl[tid] = s;
  }
  {
    const half_t* v0r = Cbn + (size_t)n * NPAD;
    const half_t* g1r = G1n + (size_t)n * NPAD;
    const half_t* g2r = G2n + (size_t)n * NPAD;
    for (int idx = tid; idx < NCOLS / 8; idx += 256) {
      const f16x8 v0 = *(const f16x8*)&v0r[idx * 8];
      const f16x8 g1 = *(const f16x8*)&g1r[idx * 8];
      const f16x8 g2 = *(const f16x8*)&g2r[idx * 8];
      const f16x8 x2 = g2 + g2 - v0;
#pragma unroll
      for (int e = 0; e < 8; ++e) {
        const int col = idx * 8 + e;
        const int b = col / CI;
        const int i = col - b * CI;
        xg[b * KILD + i] = v0[e];
        xg[b * KILD + CI + i] = g1[e];
        xg[b * KILD + 2 * CI + i] = x2[e];
      }
    }
    for (int z = tid; z < 32 * 17; z += 256) {
      const int b = z / 17;
      const int j = z - b * 17;
      *(unsigned*)&xg[b * KILD + KI_REAL + j * 2] = 0u;
    }
  }
  __syncthreads();

  const int fr = lane & 15;
  const int fk = (lane >> 4) * 8;
  f32x4 acc[2] = {};
#pragma unroll
  for (int ks = 0; ks < 7; ++ks) {
    const f16x8 a0 = *(const f16x8*)&xg[fr * KILD + ks * 32 + fk];
    const f16x8 a1 = *(const f16x8*)&xg[(16 + fr) * KILD + ks * 32 + fk];
    const f16x8 b0 = *(const f16x8*)&Wl[(wave * 16 + fr) * KILD + ks * 32 + fk];
    acc[0] = __builtin_amdgcn_mfma_f32_16x16x32_f16(a0, b0, acc[0], 0, 0, 0);
    acc[1] = __builtin_amdgcn_mfma_f32_16x16x32_f16(a1, b0, acc[1], 0, 0, 0);
  }

  const int en = lane & 15;
  const int em = (lane >> 4) * 4;
  const int o = wave * 16 + en;
  const float bo = biasl[o];
#pragma unroll
  for (int i = 0; i < 2; ++i) {
#pragma unroll
    for (int r = 0; r < 4; ++r) {
      const int b = i * 16 + em + r;
      const float hc = fast_tanh(acc[i][r] + bo);
      const size_t base = ((size_t)b * N_NODES + n) * COUT + o;
      const float h = H[base];
      const float rr = Rb[base];
      Out[base] = rr * h + (1.f - rr) * hc;
    }
  }
}

// ===========================================================================
// FALLBACK PATH (proven R4 transforms, used when ws_size is too small)
// ===========================================================================
__global__ __launch_bounds__(256, 4) void k_gate(const half_t* __restrict__ Vn,
                                                 const half_t* __restrict__ G1n,
                                                 const half_t* __restrict__ G2n,
                                                 const float* __restrict__ E,
                                                 const float* __restrict__ Wg,
                                                 const float* __restrict__ bg,
                                                 const float* __restrict__ H,
                                                 half_t* __restrict__ Cbn,
                                                 half_t* __restrict__ Cbt,
                                                 float* __restrict__ R) {
  const int n = blockIdx.y;
  const int ch = blockIdx.x;
  const int tid = threadIdx.x;
  __shared__ float En[D_EMB];
  __shared__ float bo[OCH];
  __shared__ __align__(16) float Wch[KSUP * CI * OCH];
  __shared__ float xg[3][NCOLS];

  if (tid < D_EMB) En[tid] = E[n * D_EMB + tid];
  __syncthreads();

  if (tid < OCH) {
    float a = 0.f;
#pragma unroll
    for (int d = 0; d < D_EMB; ++d) a += En[d] * bg[d * 128 + ch * OCH + tid];
    bo[tid] = a;
  }
  for (int idx = tid; idx < KSUP * CI * OCH; idx += 256) {
    const int k = idx / (CI * OCH);
    const int rem = idx - k * (CI * OCH);
    const int i = rem >> 4;
    const int o = rem & (OCH - 1);
    float a = 0.f;
#pragma unroll
    for (int d = 0; d < D_EMB; ++d)
      a += En[d] * Wg[(((size_t)d * KSUP + k) * CI + i) * 128 + ch * OCH + o];
    Wch[idx] = a;
  }
  {
    const half_t* v0r = Vn + (size_t)n * NPAD;
    const half_t* g1r = G1n + (size_t)n * NPAD;
    const half_t* g2r = G2n + (size_t)n * NPAD;
    for (int idx = tid; idx < NCOLS; idx += 256) {
      const float a0 = (float)v0r[idx];
      xg[0][idx] = a0;
      xg[1][idx] = (float)g1r[idx];
      xg[2][idx] = 2.f * (float)g2r[idx] - a0;
    }
  }
  __syncthreads();

  const int b = tid >> 3;
  const int o2 = (tid & 7) * 2;
  float a0 = bo[o2], a1 = bo[o2 + 1];
#pragma unroll 1
  for (int k = 0; k < KSUP; ++k) {
    const float* xr = &xg[k][b * CI];
    const float* wr = &Wch[k * CI * OCH + o2];
#pragma unroll 4
    for (int i = 0; i < CI; ++i) {
      const float xv = xr[i];
      const float2 wv = *(const float2*)&wr[i * OCH];
      a0 += xv * wv.x;
      a1 += xv * wv.y;
    }
  }
  const float s0 = fast_sigmoid(a0);
  const float s1 = fast_sigmoid(a1);
  const int og = ch * OCH + o2;
  if (og < COUT) {
    const float2 h = *(const float2*)&H[((size_t)b * N_NODES + n) * COUT + og];
    const half_t z0 = (half_t)(s0 * h.x);
    const half_t z1 = (half_t)(s1 * h.y);
    const int c0 = b * CI + CIN + og;
    Cbn[(size_t)n * NPAD + c0] = z0;
    Cbn[(size_t)n * NPAD + c0 + 1] = z1;
    Cbt[(size_t)c0 * LDT + n] = z0;
    Cbt[(size_t)(c0 + 1) * LDT + n] = z1;
  } else {
    float2 r = {s0, s1};
    *(float2*)&R[((size_t)b * N_NODES + n) * COUT + (og - COUT)] = r;
  }
}

__global__ __launch_bounds__(256, 4) void k_update(const half_t* __restrict__ Cbn,
                                                   const half_t* __restrict__ G1n,
                                                   const half_t* __restrict__ G2n,
                                                   const float* __restrict__ E,
                                                   const float* __restrict__ Wu,
                                                   const float* __restrict__ bu,
                                                   const float* __restrict__ H,
                                                   const float* __restrict__ R,
                                                   float* __restrict__ Out) {
  const int n = blockIdx.y;
  const int ch = blockIdx.x;
  const int tid = threadIdx.x;
  __shared__ float En[D_EMB];
  __shared__ float bo[OCH];
  __shared__ __align__(16) float Wch[KSUP * CI * OCH];
  __shared__ float xg[3][NCOLS];

  if (tid < D_EMB) En[tid] = E[n * D_EMB + tid];
  __syncthreads();

  if (tid < OCH) {
    float a = 0.f;
#pragma unroll
    for (int d = 0; d < D_EMB; ++d) a += En[d] * bu[d * COUT + ch * OCH + tid];
    bo[tid] = a;
  }
  for (int idx = tid; idx < KSUP * CI * OCH; idx += 256) {
    const int k = idx / (CI * OCH);
    const int rem = idx - k * (CI * OCH);
    const int i = rem >> 4;
    const int o = rem & (OCH - 1);
    float a = 0.f;
#pragma unroll
    for (int d = 0; d < D_EMB; ++d)
      a += En[d] * Wu[(((size_t)d * KSUP + k) * CI + i) * COUT + ch * OCH + o];
    Wch[idx] = a;
  }
  {
    const half_t* v0r = Cbn + (size_t)n * NPAD;
    const half_t* g1r = G1n + (size_t)n * NPAD;
    const half_t* g2r = G2n + (size_t)n * NPAD;
    for (int idx = tid; idx < NCOLS; idx += 256) {
      const float a0 = (float)v0r[idx];
      xg[0][idx] = a0;
      xg[1][idx] = (float)g1r[idx];
      xg[2][idx] = 2.f * (float)g2r[idx] - a0;
    }
  }
  __syncthreads();

  const int b = tid >> 3;
  const int o2 = (tid & 7) * 2;
  float a0 = bo[o2], a1 = bo[o2 + 1];
#pragma unroll 1
  for (int k = 0; k < KSUP; ++k) {
    const float* xr = &xg[k][b * CI];
    const float* wr = &Wch[k * CI * OCH + o2];
#pragma unroll 4
    for (int i = 0; i < CI; ++i) {
      const float xv = xr[i];
      const float2 wv = *(const float2*)&wr[i * OCH];
      a0 += xv * wv.x;
      a1 += xv * wv.y;
    }
  }
  const int og = ch * OCH + o2;
  const size_t base = ((size_t)b * N_NODES + n) * COUT + og;
  const float2 h = *(const float2*)&H[base];
  const float2 r = *(const float2*)&R[base];
  float2 o;
  o.x = r.x * h.x + (1.f - r.x) * fast_tanh(a0);
  o.y = r.y * h.y + (1.f - r.y) * fast_tanh(a1);
  *(float2*)&Out[base] = o;
}

// ---------------------------------------------------------------------------
extern "C" void kernel_launch(void* const* d_in, const int* in_sizes, int n_in,
                              void* d_out, int out_size, void* d_ws, size_t ws_size,
                              hipStream_t stream) {
  const float* X  = (const float*)d_in[0];
  const float* H  = (const float*)d_in[1];
  const float* E  = (const float*)d_in[2];
  const float* Wg = (const float*)d_in[3];
  const float* bg = (const float*)d_in[4];
  const float* Wu = (const float*)d_in[5];
  const float* bu = (const float*)d_in[6];
  float* out = (float*)d_out;

  const size_t SZ_P = (size_t)N_NODES * N_NODES;   // 16,777,216
  const size_t SZ_M = (size_t)NPAD * LDT;          //  8,912,896
  half_t* Pb  = (half_t*)d_ws;
  half_t* Vt  = Pb + SZ_P;
  half_t* Vn  = Vt + SZ_M;
  half_t* G1t = Vn + SZ_M;
  half_t* G1n = G1t + SZ_M;
  half_t* G2t = G1n + SZ_M;
  half_t* G2n = G2t + SZ_M;
  half_t* Cbt = G2n + SZ_M;
  half_t* Cbn = Cbt + SZ_M;
  float*    R = (float*)(Cbn + SZ_M);              // 8,388,608 f32
  // big-path extras after R:
  half_t* Wgt2 = (half_t*)(R + SZ_P / 2);          // WGT2_R*32  = 1,425,408
  half_t* E2   = Wgt2 + (size_t)WGT2_R * 32;       // 4096*32    =   131,072
  half_t* Wn   = E2 + (size_t)N_NODES * 32;        // 4096*WROW_G = 121,634,816

  const size_t need_halves =
      SZ_P + 8 * SZ_M + SZ_P /*R*/ + (size_t)WGT2_R * 32 + (size_t)N_NODES * 32 +
      (size_t)N_NODES * WROW_G;
  const bool big = (ws_size >= need_halves * sizeof(half_t));

  // common prologue
  k_softmax_p<<<N_NODES, 256, 0, stream>>>(E, Pb);
  {
    const size_t tot = (size_t)N_NODES * NCOLS;
    k_build_v0<<<(int)((tot + 255) / 256), 256, 0, stream>>>(X, H, Vt, Vn, Cbt, Cbn);
  }
  dim3 gg(NPAD / 128, N_NODES / 128);

  if (big) {
    k_wgt2<<<(WGT2_R + 255) / 256, 256, 0, stream>>>(Wg, Wu, Wgt2);
    k_e2<<<(N_NODES * 32) / 256, 256, 0, stream>>>(E, E2);
    k_wn<<<dim3(WROW_G / 64, N_NODES / 256), 256, 0, stream>>>(Wgt2, E2, Wn, WROW_G);
    k_gemm_f16<<<gg, 256, 0, stream>>>(Pb, Vt, G1n, G1t);
    k_gemm_f16<<<gg, 256, 0, stream>>>(Pb, G1t, G2n, G2t);
    k_gate_t<<<N_NODES, 256, 0, stream>>>(Vn, G1n, G2n, Wn, E, bg, H, Cbn, Cbt, R);
    k_wn<<<dim3(WROW_U / 64, N_NODES / 256), 256, 0, stream>>>(
        Wgt2 + (size_t)WROW_G * 32, E2, Wn, WROW_U);
    k_gemm_f16<<<gg, 256, 0, stream>>>(Pb, Cbt, G1n, G1t);
    k_gemm_f16<<<gg, 256, 0, stream>>>(Pb, G1t, G2n, G2t);
    k_update_t<<<N_NODES, 256, 0, stream>>>(Cbn, G1n, G2n, Wn, E, bu, H, R, out);
  } else {
    k_gemm_f16<<<gg, 256, 0, stream>>>(Pb, Vt, G1n, G1t);
    k_gemm_f16<<<gg, 256, 0, stream>>>(Pb, G1t, G2n, G2t);
    k_gate<<<dim3(128 / OCH, N_NODES), 256, 0, stream>>>(Vn, G1n, G2n, E, Wg, bg, H, Cbn, Cbt, R);
    k_gemm_f16<<<gg, 256, 0, stream>>>(Pb, Cbt, G1n, G1t);
    k_gemm_f16<<<gg, 256, 0, stream>>>(Pb, G1t, G2n, G2t);
    k_update<<<dim3(COUT / OCH, N_NODES), 256, 0, stream>>>(Cbn, G1n, G2n, E, Wu, bu, H, R, out);
  }
}

// Round 6
// 873.792 us; speedup vs baseline: 1.6348x; 1.6348x over previous
//
#include <hip/hip_runtime.h>
#include <math.h>

// Problem constants (from setup_inputs)
#define N_NODES 4096
#define BATCH   32
#define D_EMB   10
#define CIN     2
#define COUT    64
#define CI      66          // CIN + COUT
#define KSUP    3
#define NCOLS   2112        // BATCH * CI
#define NPAD    2176        // NCOLS padded to 17*128 tiles
#define LDT     4096        // t-layout row stride (m contiguous)

// MFMA-transform constants
#define KI_REAL 198         // KSUP*CI
#define KILD    232         // LDS row stride for ki (pad, mult of 8)
#define WROW_G  (128 * KILD)   // 29696 gate W entries per node
#define WROW_U  (64 * KILD)    // 14848 update W entries per node
#define WGT2_R  (WROW_G + WROW_U)  // 44544 ncols in the packed pool

typedef _Float16 half_t;
typedef __attribute__((ext_vector_type(8))) _Float16 f16x8;
typedef __attribute__((ext_vector_type(4))) _Float16 f16x4;
typedef __attribute__((ext_vector_type(2))) _Float16 f16x2;
typedef __attribute__((ext_vector_type(4))) float f32x4;

union u32h2 { unsigned u; f16x2 h; };

__device__ __forceinline__ float fast_sigmoid(float x) { return 1.f / (1.f + __expf(-x)); }
__device__ __forceinline__ float fast_tanh(float x) { return 1.f - 2.f / (__expf(2.f * x) + 1.f); }

__device__ __forceinline__ void gld_lds16(const half_t* g, half_t* l) {
  __builtin_amdgcn_global_load_lds(
      (const __attribute__((address_space(1))) void*)g,
      (__attribute__((address_space(3))) void*)l, 16, 0, 0);
}

// ---------------------------------------------------------------------------
// P[n,m] = softmax_m(relu(E[n,:].E[m,:])) stored directly as fp16.
// ---------------------------------------------------------------------------
__global__ __launch_bounds__(256) void k_softmax_p(const float* __restrict__ E,
                                                   half_t* __restrict__ Pb) {
  const int n = blockIdx.x;
  const int tid = threadIdx.x;
  __shared__ float En[D_EMB];
  __shared__ float ms[256], ss[256];
  if (tid < D_EMB) En[tid] = E[n * D_EMB + tid];
  __syncthreads();
  float en[D_EMB];
#pragma unroll
  for (int d = 0; d < D_EMB; ++d) en[d] = En[d];

  float m = -1e30f, s = 0.f;
  for (int c = tid; c < N_NODES; c += 256) {
    const float* Ec = E + c * D_EMB;
    float v = 0.f;
#pragma unroll
    for (int d = 0; d < D_EMB; ++d) v += en[d] * Ec[d];
    v = fmaxf(v, 0.f);
    if (v > m) { s *= __expf(m - v); m = v; }
    s += __expf(v - m);
  }
  ms[tid] = m; ss[tid] = s;
  __syncthreads();
  for (int off = 128; off > 0; off >>= 1) {
    if (tid < off) {
      float m2 = ms[tid + off], s2 = ss[tid + off];
      float m1 = ms[tid], s1 = ss[tid];
      float mm = fmaxf(m1, m2);
      ms[tid] = mm;
      ss[tid] = s1 * __expf(m1 - mm) + s2 * __expf(m2 - mm);
    }
    __syncthreads();
  }
  const float M = ms[0];
  const float inv = 1.f / ss[0];
  half_t* Pr = Pb + (size_t)n * N_NODES;
  for (int c = tid; c < N_NODES; c += 256) {
    const float* Ec = E + c * D_EMB;
    float v = 0.f;
#pragma unroll
    for (int d = 0; d < D_EMB; ++d) v += en[d] * Ec[d];
    v = fmaxf(v, 0.f);
    Pr[c] = (half_t)(__expf(v - M) * inv);
  }
}

// ---------------------------------------------------------------------------
// Build V0 in both layouts (+ X part of Cb in both layouts), fp16.
// ---------------------------------------------------------------------------
__global__ __launch_bounds__(256) void k_build_v0(const float* __restrict__ X,
                                                  const float* __restrict__ H,
                                                  half_t* __restrict__ Vt,
                                                  half_t* __restrict__ Vn,
                                                  half_t* __restrict__ Cbt,
                                                  half_t* __restrict__ Cbn) {
  size_t idx = (size_t)blockIdx.x * 256 + threadIdx.x;
  if (idx >= (size_t)N_NODES * NCOLS) return;
  const int m = (int)(idx / NCOLS);
  const int col = (int)(idx % NCOLS);
  const int b = col / CI;
  const int c = col % CI;
  float v;
  if (c < CIN) v = X[((size_t)b * N_NODES + m) * CIN + c];
  else         v = H[((size_t)b * N_NODES + m) * COUT + (c - CIN)];
  const half_t h = (half_t)v;
  Vn[(size_t)m * NPAD + col] = h;
  Vt[(size_t)col * LDT + m] = h;
  if (c < CIN) {
    Cbn[(size_t)m * NPAD + col] = h;
    Cbt[(size_t)col * LDT + m] = h;
  }
}

// ---------------------------------------------------------------------------
// fp16 MFMA NT-GEMM (verified R4): C[m][n] = sum_k A[m][k] * Bt[n][k]
// Ct may be nullptr (skip t-layout store).
// ---------------------------------------------------------------------------
__global__ __launch_bounds__(256) void k_gemm_f16(const half_t* __restrict__ A,
                                                  const half_t* __restrict__ Bt,
                                                  half_t* __restrict__ Cn,
                                                  half_t* __restrict__ Ct) {
  __shared__ half_t As[128 * 32];
  __shared__ half_t Bs[128 * 32];
  const int tid = threadIdx.x;
  const int lane = tid & 63;
  const int wave = tid >> 6;
  const int wm = (wave >> 1) * 64;
  const int wn = (wave & 1) * 64;
  const int rb = blockIdx.y * 128;
  const int cb = blockIdx.x * 128;

  const int srow = (lane >> 2);
  const int skg = (lane & 3) * 8;
  const half_t* ga0 = A + (size_t)(rb + wave * 32 + srow) * N_NODES + skg;
  const half_t* ga1 = ga0 + (size_t)16 * N_NODES;
  const half_t* gb0 = Bt + (size_t)(cb + wave * 32 + srow) * LDT + skg;
  const half_t* gb1 = gb0 + (size_t)16 * LDT;
  half_t* lA0 = As + wave * 1024;
  half_t* lA1 = lA0 + 512;
  half_t* lB0 = Bs + wave * 1024;
  half_t* lB1 = lB0 + 512;

  const int fr = lane & 15;
  const int fk = (lane >> 4) * 8;

  f32x4 acc[4][4] = {};

  for (int k0 = 0; k0 < N_NODES; k0 += 32) {
    __syncthreads();
    gld_lds16(ga0 + k0, lA0);
    gld_lds16(ga1 + k0, lA1);
    gld_lds16(gb0 + k0, lB0);
    gld_lds16(gb1 + k0, lB1);
    __syncthreads();

    f16x8 a[4], b[4];
#pragma unroll
    for (int i = 0; i < 4; ++i)
      a[i] = *(const f16x8*)&As[(wm + i * 16 + fr) * 32 + fk];
#pragma unroll
    for (int j = 0; j < 4; ++j)
      b[j] = *(const f16x8*)&Bs[(wn + j * 16 + fr) * 32 + fk];
#pragma unroll
    for (int i = 0; i < 4; ++i)
#pragma unroll
      for (int j = 0; j < 4; ++j)
        acc[i][j] = __builtin_amdgcn_mfma_f32_16x16x32_f16(a[i], b[j], acc[i][j], 0, 0, 0);
  }

  const int en = lane & 15;
  const int em = (lane >> 4) * 4;
#pragma unroll
  for (int i = 0; i < 4; ++i) {
#pragma unroll
    for (int j = 0; j < 4; ++j) {
      const int m0 = rb + wm + i * 16 + em;
      const int n = cb + wn + j * 16 + en;
      half_t h0 = (half_t)acc[i][j][0];
      half_t h1 = (half_t)acc[i][j][1];
      half_t h2 = (half_t)acc[i][j][2];
      half_t h3 = (half_t)acc[i][j][3];
      if (Ct) {
        f16x4 t4 = {h0, h1, h2, h3};
        *(f16x4*)&Ct[(size_t)n * LDT + m0] = t4;
      }
      Cn[(size_t)(m0 + 0) * NPAD + n] = h0;
      Cn[(size_t)(m0 + 1) * NPAD + n] = h1;
      Cn[(size_t)(m0 + 2) * NPAD + n] = h2;
      Cn[(size_t)(m0 + 3) * NPAD + n] = h3;
    }
  }
}

// ---------------------------------------------------------------------------
// WT2: d-pair-packed fp16 pool, L2-resident (891 KB).
// WT2[dp * WGT2_R + r] = half2( pool[2dp][ki][o], pool[2dp+1][ki][o] )
// where r < WROW_G: gate, o = r/KILD, ki = r%KILD (ki>=198 -> 0);
//       r >= WROW_G: update with r2 = r-WROW_G.
// ---------------------------------------------------------------------------
__global__ __launch_bounds__(256) void k_wgt2(const float* __restrict__ Wg,
                                              const float* __restrict__ Wu,
                                              unsigned* __restrict__ WT2) {
  const int r = blockIdx.x * 256 + threadIdx.x;
  if (r >= WGT2_R) return;
  const float* pool;
  int o, ki, ostr;
  if (r < WROW_G) { o = r / KILD; ki = r % KILD; pool = Wg; ostr = 128; }
  else { int r2 = r - WROW_G; o = r2 / KILD; ki = r2 % KILD; pool = Wu; ostr = 64; }
#pragma unroll
  for (int dp = 0; dp < 5; ++dp) {
    u32h2 v; v.h = f16x2{(half_t)0.f, (half_t)0.f};
    if (ki < KI_REAL) {
      const int k = ki / CI;
      const int i = ki % CI;
      v.h[0] = (half_t)pool[(((size_t)(2 * dp) * KSUP + k) * CI + i) * ostr + o];
      v.h[1] = (half_t)pool[(((size_t)(2 * dp + 1) * KSUP + k) * CI + i) * ostr + o];
    }
    WT2[(size_t)dp * WGT2_R + r] = v.u;
  }
}

// ---------------------------------------------------------------------------
// Gate transform (MFMA, in-block W compute):
//   Wl[o][ki] = sum_d E[n,d] * pool[d][ki][o]   (fdot2, fp32 acc, L2 reads)
//   ZR[b][o]  = sigmoid( sum_ki xg[b][ki] * Wl[o][ki] + bias[o] )
//   o<64 -> Cb Z-part (both layouts); o>=64 -> R (fp16).
// ---------------------------------------------------------------------------
__global__ __launch_bounds__(256) void k_gate_t(const half_t* __restrict__ Vn,
                                                const half_t* __restrict__ G1n,
                                                const half_t* __restrict__ G2n,
                                                const unsigned* __restrict__ WT2,
                                                const float* __restrict__ E,
                                                const float* __restrict__ bg,
                                                const float* __restrict__ H,
                                                half_t* __restrict__ Cbn,
                                                half_t* __restrict__ Cbt,
                                                half_t* __restrict__ Rb) {
  const int n = blockIdx.x;
  const int tid = threadIdx.x;
  const int lane = tid & 63;
  const int wave = tid >> 6;
  __shared__ half_t Wl[128 * KILD];   // 59392 B
  __shared__ half_t xg[32 * KILD];    // 14848 B
  __shared__ float biasl[128];

  // E[n] packed into half2 pairs (uniform across block)
  f16x2 e2p[5];
#pragma unroll
  for (int dp = 0; dp < 5; ++dp) {
    e2p[dp][0] = (half_t)E[n * D_EMB + 2 * dp];
    e2p[dp][1] = (half_t)E[n * D_EMB + 2 * dp + 1];
  }

  // 1) Wl = E[n] . pool   (29696 entries; thread -> octets of 8 ncols)
  for (int base = tid * 8; base < WROW_G; base += 2048) {
    float acc[8] = {};
#pragma unroll
    for (int dp = 0; dp < 5; ++dp) {
      const unsigned* wrow = WT2 + (size_t)dp * WGT2_R + base;
      uint4 wa = *(const uint4*)wrow;
      uint4 wb = *(const uint4*)(wrow + 4);
      u32h2 c0, c1, c2, c3;
      c0.u = wa.x; c1.u = wa.y; c2.u = wa.z; c3.u = wa.w;
      acc[0] = __builtin_amdgcn_fdot2(c0.h, e2p[dp], acc[0], false);
      acc[1] = __builtin_amdgcn_fdot2(c1.h, e2p[dp], acc[1], false);
      acc[2] = __builtin_amdgcn_fdot2(c2.h, e2p[dp], acc[2], false);
      acc[3] = __builtin_amdgcn_fdot2(c3.h, e2p[dp], acc[3], false);
      c0.u = wb.x; c1.u = wb.y; c2.u = wb.z; c3.u = wb.w;
      acc[4] = __builtin_amdgcn_fdot2(c0.h, e2p[dp], acc[4], false);
      acc[5] = __builtin_amdgcn_fdot2(c1.h, e2p[dp], acc[5], false);
      acc[6] = __builtin_amdgcn_fdot2(c2.h, e2p[dp], acc[6], false);
      acc[7] = __builtin_amdgcn_fdot2(c3.h, e2p[dp], acc[7], false);
    }
    f16x8 w8;
#pragma unroll
    for (int e = 0; e < 8; ++e) w8[e] = (half_t)acc[e];
    *(f16x8*)&Wl[base] = w8;
  }

  // 2) bias
  if (tid < 128) {
    float s = 0.f;
#pragma unroll
    for (int d = 0; d < D_EMB; ++d) s += E[n * D_EMB + d] * bg[d * 128 + tid];
    biasl[tid] = s;
  }

  // 3) xg[b][ki]: ki = k*CI+i; pad [198,232) zeros
  {
    const half_t* v0r = Vn + (size_t)n * NPAD;
    const half_t* g1r = G1n + (size_t)n * NPAD;
    const half_t* g2r = G2n + (size_t)n * NPAD;
    for (int idx = tid; idx < NCOLS / 8; idx += 256) {
      const f16x8 v0 = *(const f16x8*)&v0r[idx * 8];
      const f16x8 g1 = *(const f16x8*)&g1r[idx * 8];
      const f16x8 g2 = *(const f16x8*)&g2r[idx * 8];
      const f16x8 x2 = g2 + g2 - v0;
#pragma unroll
      for (int e = 0; e < 8; ++e) {
        const int col = idx * 8 + e;
        const int b = col / CI;
        const int i = col - b * CI;
        xg[b * KILD + i] = v0[e];
        xg[b * KILD + CI + i] = g1[e];
        xg[b * KILD + 2 * CI + i] = x2[e];
      }
    }
    for (int z = tid; z < 32 * 17; z += 256) {
      const int b = z / 17;
      const int j = z - b * 17;
      *(unsigned*)&xg[b * KILD + KI_REAL + j * 2] = 0u;
    }
  }
  __syncthreads();

  // 4) MFMA: wave w -> o in [w*32, w*32+32); rows = b (2 m-tiles)
  const int fr = lane & 15;
  const int fk = (lane >> 4) * 8;
  f32x4 acc[2][2] = {};
#pragma unroll
  for (int ks = 0; ks < 7; ++ks) {
    const f16x8 a0 = *(const f16x8*)&xg[fr * KILD + ks * 32 + fk];
    const f16x8 a1 = *(const f16x8*)&xg[(16 + fr) * KILD + ks * 32 + fk];
    const f16x8 b0 = *(const f16x8*)&Wl[(wave * 32 + fr) * KILD + ks * 32 + fk];
    const f16x8 b1 = *(const f16x8*)&Wl[(wave * 32 + 16 + fr) * KILD + ks * 32 + fk];
    acc[0][0] = __builtin_amdgcn_mfma_f32_16x16x32_f16(a0, b0, acc[0][0], 0, 0, 0);
    acc[0][1] = __builtin_amdgcn_mfma_f32_16x16x32_f16(a0, b1, acc[0][1], 0, 0, 0);
    acc[1][0] = __builtin_amdgcn_mfma_f32_16x16x32_f16(a1, b0, acc[1][0], 0, 0, 0);
    acc[1][1] = __builtin_amdgcn_mfma_f32_16x16x32_f16(a1, b1, acc[1][1], 0, 0, 0);
  }

  // 5) epilogue: col(en)=o, row=(lane>>4)*4+reg = b. waves 0,1 -> Z; 2,3 -> R.
  const int en = lane & 15;
  const int em = (lane >> 4) * 4;
#pragma unroll
  for (int i = 0; i < 2; ++i) {
#pragma unroll
    for (int j = 0; j < 2; ++j) {
      const int o = wave * 32 + j * 16 + en;
      const float bo = biasl[o];
#pragma unroll
      for (int r = 0; r < 4; ++r) {
        const int b = i * 16 + em + r;
        const float s = fast_sigmoid(acc[i][j][r] + bo);
        if (wave < 2) {
          const float h = H[((size_t)b * N_NODES + n) * COUT + o];
          const half_t z = (half_t)(s * h);
          const int c0 = b * CI + CIN + o;
          Cbn[(size_t)n * NPAD + c0] = z;
          Cbt[(size_t)c0 * LDT + n] = z;
        } else {
          Rb[((size_t)b * N_NODES + n) * COUT + (o - 64)] = (half_t)s;
        }
      }
    }
  }
}

// ---------------------------------------------------------------------------
// Update transform (MFMA, in-block W compute) + final gating.
// ---------------------------------------------------------------------------
__global__ __launch_bounds__(256) void k_update_t(const half_t* __restrict__ Cbn,
                                                  const half_t* __restrict__ G1n,
                                                  const half_t* __restrict__ G2n,
                                                  const unsigned* __restrict__ WT2,
                                                  const float* __restrict__ E,
                                                  const float* __restrict__ bu,
                                                  const float* __restrict__ H,
                                                  const half_t* __restrict__ Rb,
                                                  float* __restrict__ Out) {
  const int n = blockIdx.x;
  const int tid = threadIdx.x;
  const int lane = tid & 63;
  const int wave = tid >> 6;
  __shared__ half_t Wl[64 * KILD];    // 29696 B
  __shared__ half_t xg[32 * KILD];
  __shared__ float biasl[64];

  f16x2 e2p[5];
#pragma unroll
  for (int dp = 0; dp < 5; ++dp) {
    e2p[dp][0] = (half_t)E[n * D_EMB + 2 * dp];
    e2p[dp][1] = (half_t)E[n * D_EMB + 2 * dp + 1];
  }

  for (int base = tid * 8; base < WROW_U; base += 2048) {
    float acc[8] = {};
#pragma unroll
    for (int dp = 0; dp < 5; ++dp) {
      const unsigned* wrow = WT2 + (size_t)dp * WGT2_R + WROW_G + base;
      uint4 wa = *(const uint4*)wrow;
      uint4 wb = *(const uint4*)(wrow + 4);
      u32h2 c0, c1, c2, c3;
      c0.u = wa.x; c1.u = wa.y; c2.u = wa.z; c3.u = wa.w;
      acc[0] = __builtin_amdgcn_fdot2(c0.h, e2p[dp], acc[0], false);
      acc[1] = __builtin_amdgcn_fdot2(c1.h, e2p[dp], acc[1], false);
      acc[2] = __builtin_amdgcn_fdot2(c2.h, e2p[dp], acc[2], false);
      acc[3] = __builtin_amdgcn_fdot2(c3.h, e2p[dp], acc[3], false);
      c0.u = wb.x; c1.u = wb.y; c2.u = wb.z; c3.u = wb.w;
      acc[4] = __builtin_amdgcn_fdot2(c0.h, e2p[dp], acc[4], false);
      acc[5] = __builtin_amdgcn_fdot2(c1.h, e2p[dp], acc[5], false);
      acc[6] = __builtin_amdgcn_fdot2(c2.h, e2p[dp], acc[6], false);
      acc[7] = __builtin_amdgcn_fdot2(c3.h, e2p[dp], acc[7], false);
    }
    f16x8 w8;
#pragma unroll
    for (int e = 0; e < 8; ++e) w8[e] = (half_t)acc[e];
    *(f16x8*)&Wl[base] = w8;
  }

  if (tid < 64) {
    float s = 0.f;
#pragma unroll
    for (int d = 0; d < D_EMB; ++d) s += E[n * D_EMB + d] * bu[d * COUT + tid];
    biasl[tid] = s;
  }

  {
    const half_t* v0r = Cbn + (size_t)n * NPAD;
    const half_t* g1r = G1n + (size_t)n * NPAD;
    const half_t* g2r = G2n + (size_t)n * NPAD;
    for (int idx = tid; idx < NCOLS / 8; idx += 256) {
      const f16x8 v0 = *(const f16x8*)&v0r[idx * 8];
      const f16x8 g1 = *(const f16x8*)&g1r[idx * 8];
      const f16x8 g2 = *(const f16x8*)&g2r[idx * 8];
      const f16x8 x2 = g2 + g2 - v0;
#pragma unroll
      for (int e = 0; e < 8; ++e) {
        const int col = idx * 8 + e;
        const int b = col / CI;
        const int i = col - b * CI;
        xg[b * KILD + i] = v0[e];
        xg[b * KILD + CI + i] = g1[e];
        xg[b * KILD + 2 * CI + i] = x2[e];
      }
    }
    for (int z = tid; z < 32 * 17; z += 256) {
      const int b = z / 17;
      const int j = z - b * 17;
      *(unsigned*)&xg[b * KILD + KI_REAL + j * 2] = 0u;
    }
  }
  __syncthreads();

  // wave w -> o in [w*16, w*16+16)
  const int fr = lane & 15;
  const int fk = (lane >> 4) * 8;
  f32x4 acc[2] = {};
#pragma unroll
  for (int ks = 0; ks < 7; ++ks) {
    const f16x8 a0 = *(const f16x8*)&xg[fr * KILD + ks * 32 + fk];
    const f16x8 a1 = *(const f16x8*)&xg[(16 + fr) * KILD + ks * 32 + fk];
    const f16x8 b0 = *(const f16x8*)&Wl[(wave * 16 + fr) * KILD + ks * 32 + fk];
    acc[0] = __builtin_amdgcn_mfma_f32_16x16x32_f16(a0, b0, acc[0], 0, 0, 0);
    acc[1] = __builtin_amdgcn_mfma_f32_16x16x32_f16(a1, b0, acc[1], 0, 0, 0);
  }

  const int en = lane & 15;
  const int em = (lane >> 4) * 4;
  const int o = wave * 16 + en;
  const float bo = biasl[o];
#pragma unroll
  for (int i = 0; i < 2; ++i) {
#pragma unroll
    for (int r = 0; r < 4; ++r) {
      const int b = i * 16 + em + r;
      const float hc = fast_tanh(acc[i][r] + bo);
      const size_t base = ((size_t)b * N_NODES + n) * COUT + o;
      const float h = H[base];
      const float rr = (float)Rb[base];
      Out[base] = rr * h + (1.f - rr) * hc;
    }
  }
}

// ---------------------------------------------------------------------------
extern "C" void kernel_launch(void* const* d_in, const int* in_sizes, int n_in,
                              void* d_out, int out_size, void* d_ws, size_t ws_size,
                              hipStream_t stream) {
  const float* X  = (const float*)d_in[0];
  const float* H  = (const float*)d_in[1];
  const float* E  = (const float*)d_in[2];
  const float* Wg = (const float*)d_in[3];
  const float* bg = (const float*)d_in[4];
  const float* Wu = (const float*)d_in[5];
  const float* bu = (const float*)d_in[6];
  float* out = (float*)d_out;

  // Workspace (halves): ~88.0M h = 176 MB  (<243 MB known floor)
  const size_t SZ_P = (size_t)N_NODES * N_NODES;   // 16,777,216
  const size_t SZ_M = (size_t)NPAD * LDT;          //  8,912,896
  half_t* Pb  = (half_t*)d_ws;
  half_t* Vt  = Pb + SZ_P;
  half_t* Vn  = Vt + SZ_M;
  half_t* G1t = Vn + SZ_M;
  half_t* G1n = G1t + SZ_M;
  half_t* G2n = G1n + SZ_M;
  half_t* Cbt = G2n + SZ_M;
  half_t* Cbn = Cbt + SZ_M;
  half_t* Rb  = Cbn + SZ_M;                         // B*N*COUT fp16
  unsigned* WT2 = (unsigned*)(Rb + (size_t)BATCH * N_NODES * COUT);  // 5*WGT2_R u32

  // 1. adjacency + inputs + packed pool
  k_softmax_p<<<N_NODES, 256, 0, stream>>>(E, Pb);
  {
    const size_t tot = (size_t)N_NODES * NCOLS;
    k_build_v0<<<(int)((tot + 255) / 256), 256, 0, stream>>>(X, H, Vt, Vn, Cbt, Cbn);
  }
  k_wgt2<<<(WGT2_R + 255) / 256, 256, 0, stream>>>(Wg, Wu, WT2);

  dim3 gg(NPAD / 128, N_NODES / 128);
  // 2. gate propagation + transform
  k_gemm_f16<<<gg, 256, 0, stream>>>(Pb, Vt, G1n, G1t);
  k_gemm_f16<<<gg, 256, 0, stream>>>(Pb, G1t, G2n, nullptr);
  k_gate_t<<<N_NODES, 256, 0, stream>>>(Vn, G1n, G2n, WT2, E, bg, H, Cbn, Cbt, Rb);
  // 3. update propagation + transform + output
  k_gemm_f16<<<gg, 256, 0, stream>>>(Pb, Cbt, G1n, G1t);
  k_gemm_f16<<<gg, 256, 0, stream>>>(Pb, G1t, G2n, nullptr);
  k_update_t<<<N_NODES, 256, 0, stream>>>(Cbn, G1n, G2n, WT2, E, bu, H, Rb, out);
}